// Round 7
// baseline (313.940 us; speedup 1.0000x reference)
//
#include <hip/hip_runtime.h>

#define N_NODES 50000
#define N_EDGES 800000
#define D 128
#define NBUCK 196   // ceil(50000/256) buckets of 256 nodes (dst>>8)
#define CAP 4800    // per-bucket capacity; mean 4096, sigma ~64 -> 11 sigma
#define CHUNK 4096  // edges per passA block (4/thread at 1024 threads)
#define PA_BLKS ((N_EDGES + CHUNK - 1) / CHUNK)  // 196
#define FB_BLKS 3125                             // N_NODES*64/1024
#define WT_BLKS 16                               // 16384/1024
#define GSTRIDE 16  // gcur padding: 1 counter per 64B line

typedef __attribute__((ext_vector_type(8))) short short8;
typedef __attribute__((ext_vector_type(4))) float f32x4;

__device__ __forceinline__ unsigned short f2bf(float f) {
    unsigned u = __float_as_uint(f);
    u += 0x7fff + ((u >> 16) & 1);  // RNE
    return (unsigned short)(u >> 16);
}
__device__ __forceinline__ float lo16f(unsigned u) { return __uint_as_float(u << 16); }
__device__ __forceinline__ float hi16f(unsigned u) { return __uint_as_float(u & 0xffff0000u); }

// ---------------------------------------------------------------------------
// K1 (UNCHANGED from R6): passA per-block LDS histogram -> one global
// reservation per (block,bucket) -> contiguous ~21-entry runs (write
// merging), 1024 threads. fb/Wt conversion in the same grid.
// ---------------------------------------------------------------------------
__global__ __launch_bounds__(1024) void prep_passA(
    const float2* __restrict__ feat2, unsigned* __restrict__ fb,
    const float* __restrict__ W, unsigned short* __restrict__ Wt,
    const int* __restrict__ esrc, const int* __restrict__ edst,
    const float* __restrict__ ew, int* __restrict__ gcur,
    uint2* __restrict__ tmp) {
    __shared__ int lh[NBUCK], lbase[NBUCK], lcur[NBUCK];
    int blk = blockIdx.x, t = threadIdx.x;

    if (blk >= PA_BLKS) {
        int b2 = blk - PA_BLKS;
        if (b2 < FB_BLKS) {
            int i = b2 * 1024 + t;
            float2 f = feat2[i];
            fb[i] = (unsigned)f2bf(f.x) | ((unsigned)f2bf(f.y) << 16);
        } else {
            int idx = (b2 - FB_BLKS) * 1024 + t;  // 16384 weight elements
            int n = idx >> 7, k = idx & 127;
            Wt[idx] = f2bf(W[k * 128 + n]);
        }
        return;
    }

    // ---- passA ----
    for (int i = t; i < NBUCK; i += 1024) lh[i] = 0;
    __syncthreads();
    int e0 = blk * CHUNK;
    unsigned key[4];
    float wv[4];
#pragma unroll
    for (int j = 0; j < 4; ++j) {
        int e = e0 + j * 1024 + t;
        if (e < N_EDGES) {
            int src = esrc[e], dd = edst[e];
            key[j] = (unsigned)src | ((unsigned)(dd & 255) << 16) |
                     ((unsigned)(dd >> 8) << 24);
            wv[j] = ew[e];
            atomicAdd(&lh[dd >> 8], 1);
        } else key[j] = 0xff000000u;  // invalid bucket marker
    }
    __syncthreads();
    for (int i = t; i < NBUCK; i += 1024) {
        lbase[i] = atomicAdd(&gcur[i * GSTRIDE], lh[i]);
        lcur[i] = 0;
    }
    __syncthreads();
#pragma unroll
    for (int j = 0; j < 4; ++j) {
        int b = key[j] >> 24;
        if (b < NBUCK) {
            int r = atomicAdd(&lcur[b], 1);
            tmp[(size_t)b * CAP + lbase[b] + r] =
                make_uint2(key[j] & 0x00ffffffu, __float_as_uint(wv[j]));
        }
    }
}

// ---------------------------------------------------------------------------
// K2 (UNCHANGED from R6): per-bucket counting sort -> offsets[] +
// per-node-grouped sw, 1024 threads/block, seg cached in registers.
// ---------------------------------------------------------------------------
__global__ __launch_bounds__(1024) void passB(const int* __restrict__ gcur,
                                              const uint2* __restrict__ tmp,
                                              int* __restrict__ offsets,
                                              uint2* __restrict__ sw) {
    __shared__ int hist[256], ps[256];
    int b = blockIdx.x, t = threadIdx.x;

    if (t < 256) ps[t] = (t < b) ? gcur[t * GSTRIDE] : 0;
    __syncthreads();
    for (int off = 128; off > 0; off >>= 1) {
        if (t < off) ps[t] += ps[t + off];
        __syncthreads();
    }
    int base = ps[0];
    int cnt = gcur[b * GSTRIDE];
    if (t < 256) hist[t] = 0;
    __syncthreads();

    const uint2* seg = tmp + (size_t)b * CAP;
    uint2 ent[5];
#pragma unroll
    for (int j = 0; j < 5; ++j) {
        int i = t + j * 1024;
        if (i < cnt) {
            ent[j] = seg[i];
            atomicAdd(&hist[ent[j].x >> 16], 1);
        }
    }
    __syncthreads();

    int h = 0;
    if (t < 256) { h = hist[t]; ps[t] = h; }
    __syncthreads();
    for (int off = 1; off < 256; off <<= 1) {
        int x = 0;
        if (t < 256 && t >= off) x = ps[t - off];
        __syncthreads();
        if (t < 256) ps[t] += x;
        __syncthreads();
    }
    int o = 0;
    if (t < 256) {
        o = base + ps[t] - h;  // exclusive within-bucket + bucket base
        int node = b * 256 + t;
        if (node < N_NODES) offsets[node] = o;
    }
    if (b == NBUCK - 1 && t == 0) offsets[N_NODES] = N_EDGES;
    __syncthreads();
    if (t < 256) hist[t] = o;  // reuse as cursor
    __syncthreads();
#pragma unroll
    for (int j = 0; j < 5; ++j) {
        int i = t + j * 1024;
        if (i < cnt) {
            int pos = atomicAdd(&hist[ent[j].x >> 16], 1);
            sw[pos] = make_uint2(ent[j].x & 0xffffu, ent[j].y);
        }
    }
}

// ---------------------------------------------------------------------------
// K3 (CHANGED — fabric-ceiling falsification probe): block = 16 nodes, wave
// aggregates 4. Gather layout widened to dwordx2: lanes 0-31 carry even-slot
// edges, lanes 32-63 odd-slot edges; each half covers a full 256B row
// (32 lanes x 8B), so one batch = 32 edges in 16 VMEM instructions (2x the
// per-wave outstanding-edge window of R4/R6 at the same per-edge cost).
// Fabric bytes/edge unchanged (one 256B row request either way): if agg
// stays ~47us the ~2.45 TB/s plateau is a real fabric/L3 random-access
// ceiling; if it drops, the limiter was the VMEM issue window.
// Batch-32 makes mean-degree-16 nodes single-pass -> pn prefetch deleted.
// Halves combined per node via 4x shfl_xor(.,32); lane (half,li) then owns
// Arows dword li*2+half (dims 4li+2half..+1). deg>32 nodes take the rare
// nfull loop (P~1e-4). Tail clamp-pads with zeroed weights as before.
// GEMM epilogue unchanged.
// mfma_f32_16x16x32_bf16: A[m=lane&15][k=quad*8+j], B[k][n=lane&15],
// D row=quad*4+reg, col=lane&15 (verified in prior rounds).
// ---------------------------------------------------------------------------
__global__ __launch_bounds__(256, 2) void agg_gemm(const int* __restrict__ offsets,
                                                   const uint2* __restrict__ sw,
                                                   const unsigned* __restrict__ fb,
                                                   const unsigned short* __restrict__ Wt,
                                                   float* __restrict__ out) {
    __shared__ unsigned Arows[16][68];
    int wave = threadIdx.x >> 6;
    int lane = threadIdx.x & 63;
    int half = lane >> 5;   // 0: even-slot edges, 1: odd-slot edges
    int li   = lane & 31;   // dim-group: dims [4*li, 4*li+4)
    int row0 = blockIdx.x * 16;

#pragma unroll 1
    for (int i = 0; i < 4; ++i) {
        int n = __builtin_amdgcn_readfirstlane(row0 + wave * 4 + i);
        int b = offsets[n], e2 = offsets[n + 1];
        float a0 = 0.f, a1 = 0.f, a2 = 0.f, a3 = 0.f;
        int e = b;
        int nfull = (e2 - b) >> 5;

        uint2 p[32];
        {   // preload first batch (clamped; OOB-safe: sw is followed by fb in ws)
            int rem = e2 - e;
#pragma unroll
            for (int j = 0; j < 32; ++j) {
                int idx = (j < rem) ? j : (rem > 0 ? rem - 1 : 0);
                p[j] = sw[e + idx];
            }
        }
#pragma unroll 1
        for (int t = 0; t < nfull; ++t) {  // rare: deg > 32
            uint2 u[16];
#pragma unroll
            for (int k = 0; k < 16; ++k) {
                unsigned s = half ? p[2 * k + 1].x : p[2 * k].x;
                u[k] = *reinterpret_cast<const uint2*>(fb + (size_t)s * 64 + li * 2);
            }
#pragma unroll
            for (int k = 0; k < 16; ++k) {
                float w = __uint_as_float(half ? p[2 * k + 1].y : p[2 * k].y);
                a0 += w * lo16f(u[k].x); a1 += w * hi16f(u[k].x);
                a2 += w * lo16f(u[k].y); a3 += w * hi16f(u[k].y);
            }
            e += 32;
            int rem = e2 - e;
#pragma unroll
            for (int j = 0; j < 32; ++j) {
                int idx = (j < rem) ? j : (rem > 0 ? rem - 1 : 0);
                p[j] = sw[e + idx];
            }
        }
        int rem = e2 - e;
        if (rem > 0) {  // common path: one clamp-padded batch of <=32 edges
            uint2 u[16];
#pragma unroll
            for (int k = 0; k < 16; ++k) {
                unsigned s = half ? p[2 * k + 1].x : p[2 * k].x;
                u[k] = *reinterpret_cast<const uint2*>(fb + (size_t)s * 64 + li * 2);
            }
#pragma unroll
            for (int k = 0; k < 16; ++k) {
                int jj = 2 * k + half;
                float w = (jj < rem)
                              ? __uint_as_float(half ? p[2 * k + 1].y : p[2 * k].y)
                              : 0.f;
                a0 += w * lo16f(u[k].x); a1 += w * hi16f(u[k].x);
                a2 += w * lo16f(u[k].y); a3 += w * hi16f(u[k].y);
            }
        }
        // combine halves (lane i / i+32 hold partial sums of the same dims)
        a0 += __shfl_xor(a0, 32); a1 += __shfl_xor(a1, 32);
        a2 += __shfl_xor(a2, 32); a3 += __shfl_xor(a3, 32);
        // this lane owns Arows dword li*2+half = dims (4li+2half, 4li+2half+1)
        float ax = half ? a2 : a0;
        float ay = half ? a3 : a1;
        unsigned us = fb[(size_t)n * 64 + li * 2 + half];  // self row, same dword
        float rx = 0.5f * (ax + lo16f(us));
        float ry = 0.5f * (ay + hi16f(us));
        Arows[wave * 4 + i][li * 2 + half] =
            (unsigned)f2bf(rx) | ((unsigned)f2bf(ry) << 16);
    }
    __syncthreads();

    int quad = lane >> 4;
    int col  = lane & 15;
    short8 a[4];
#pragma unroll
    for (int kk = 0; kk < 4; ++kk)
        a[kk] = *reinterpret_cast<const short8*>(&Arows[col][kk * 16 + quad * 4]);

#pragma unroll
    for (int ii = 0; ii < 2; ++ii) {
        int n0 = wave * 2 + ii;
        const short8* bp = reinterpret_cast<const short8*>(Wt) + ((n0 * 16 + col) * 16 + quad);
        f32x4 acc = {0.f, 0.f, 0.f, 0.f};
        acc = __builtin_amdgcn_mfma_f32_16x16x32_bf16(a[0], bp[0],  acc, 0, 0, 0);
        acc = __builtin_amdgcn_mfma_f32_16x16x32_bf16(a[1], bp[4],  acc, 0, 0, 0);
        acc = __builtin_amdgcn_mfma_f32_16x16x32_bf16(a[2], bp[8],  acc, 0, 0, 0);
        acc = __builtin_amdgcn_mfma_f32_16x16x32_bf16(a[3], bp[12], acc, 0, 0, 0);
#pragma unroll
        for (int rr = 0; rr < 4; ++rr)
            out[(size_t)(row0 + quad * 4 + rr) * D + n0 * 16 + col] = acc[rr];
    }
}

// ---------------------------------------------------------------------------
extern "C" void kernel_launch(void* const* d_in, const int* in_sizes, int n_in,
                              void* d_out, int out_size, void* d_ws, size_t ws_size,
                              hipStream_t stream) {
    const float* feat = (const float*)d_in[0];
    const int*   esrc = (const int*)d_in[1];
    const int*   edst = (const int*)d_in[2];
    const float* ew   = (const float*)d_in[3];
    const float* W    = (const float*)d_in[4];
    float*       out  = (float*)d_out;

    char* ws = (char*)d_ws;
    uint2*          sw      = (uint2*)(ws + 0);                   //  6,400,000
    unsigned*       fb      = (unsigned*)(ws + 6400000);          // 12,800,000
    int*            offsets = (int*)(ws + 19200000);              //    200,004
    unsigned short* Wt      = (unsigned short*)(ws + 19400064);   //     32,768
    int*            gcur    = (int*)(ws + 19432832);              //  12,544 (padded)
    // tmp (7.53 MB) aliases d_out, dead until agg_gemm overwrites it.
    uint2* tmp = (uint2*)d_out;

    hipMemsetAsync(gcur, 0, NBUCK * GSTRIDE * sizeof(int), stream);
    prep_passA<<<PA_BLKS + FB_BLKS + WT_BLKS, 1024, 0, stream>>>(
        (const float2*)feat, fb, W, Wt, esrc, edst, ew, gcur, tmp);
    passB<<<NBUCK, 1024, 0, stream>>>(gcur, tmp, offsets, sw);
    agg_gemm<<<N_NODES / 16, 256, 0, stream>>>(offsets, sw, fb, Wt, out);
}

// Round 8
// 147.469 us; speedup vs baseline: 2.1288x; 2.1288x over previous
//
#include <hip/hip_runtime.h>

#define N_NODES 50000
#define N_EDGES 800000
#define D 128
#define NBUCK 196   // ceil(50000/256) buckets of 256 nodes (dst>>8)
#define CAP 4800    // per-bucket capacity; mean 4096, sigma ~64 -> 11 sigma
#define CHUNK 4096  // edges per passA block (4/thread at 1024 threads)
#define PA_BLKS ((N_EDGES + CHUNK - 1) / CHUNK)  // 196
#define FB_BLKS 3125                             // N_NODES*64/1024
#define WT_BLKS 16                               // 16384/1024
#define GSTRIDE 16  // gcur padding: 1 counter per 64B line

typedef __attribute__((ext_vector_type(8))) short short8;
typedef __attribute__((ext_vector_type(4))) float f32x4;

__device__ __forceinline__ unsigned short f2bf(float f) {
    unsigned u = __float_as_uint(f);
    u += 0x7fff + ((u >> 16) & 1);  // RNE
    return (unsigned short)(u >> 16);
}
__device__ __forceinline__ float lo16f(unsigned u) { return __uint_as_float(u << 16); }
__device__ __forceinline__ float hi16f(unsigned u) { return __uint_as_float(u & 0xffff0000u); }

// ---------------------------------------------------------------------------
// K1 (UNCHANGED from R6): passA per-block LDS histogram -> one global
// reservation per (block,bucket) -> contiguous ~21-entry runs (write
// merging), 1024 threads. fb/Wt conversion in the same grid.
// ---------------------------------------------------------------------------
__global__ __launch_bounds__(1024) void prep_passA(
    const float2* __restrict__ feat2, unsigned* __restrict__ fb,
    const float* __restrict__ W, unsigned short* __restrict__ Wt,
    const int* __restrict__ esrc, const int* __restrict__ edst,
    const float* __restrict__ ew, int* __restrict__ gcur,
    uint2* __restrict__ tmp) {
    __shared__ int lh[NBUCK], lbase[NBUCK], lcur[NBUCK];
    int blk = blockIdx.x, t = threadIdx.x;

    if (blk >= PA_BLKS) {
        int b2 = blk - PA_BLKS;
        if (b2 < FB_BLKS) {
            int i = b2 * 1024 + t;
            float2 f = feat2[i];
            fb[i] = (unsigned)f2bf(f.x) | ((unsigned)f2bf(f.y) << 16);
        } else {
            int idx = (b2 - FB_BLKS) * 1024 + t;  // 16384 weight elements
            int n = idx >> 7, k = idx & 127;
            Wt[idx] = f2bf(W[k * 128 + n]);
        }
        return;
    }

    // ---- passA ----
    for (int i = t; i < NBUCK; i += 1024) lh[i] = 0;
    __syncthreads();
    int e0 = blk * CHUNK;
    unsigned key[4];
    float wv[4];
#pragma unroll
    for (int j = 0; j < 4; ++j) {
        int e = e0 + j * 1024 + t;
        if (e < N_EDGES) {
            int src = esrc[e], dd = edst[e];
            key[j] = (unsigned)src | ((unsigned)(dd & 255) << 16) |
                     ((unsigned)(dd >> 8) << 24);
            wv[j] = ew[e];
            atomicAdd(&lh[dd >> 8], 1);
        } else key[j] = 0xff000000u;  // invalid bucket marker
    }
    __syncthreads();
    for (int i = t; i < NBUCK; i += 1024) {
        lbase[i] = atomicAdd(&gcur[i * GSTRIDE], lh[i]);
        lcur[i] = 0;
    }
    __syncthreads();
#pragma unroll
    for (int j = 0; j < 4; ++j) {
        int b = key[j] >> 24;
        if (b < NBUCK) {
            int r = atomicAdd(&lcur[b], 1);
            tmp[(size_t)b * CAP + lbase[b] + r] =
                make_uint2(key[j] & 0x00ffffffu, __float_as_uint(wv[j]));
        }
    }
}

// ---------------------------------------------------------------------------
// K2 (UNCHANGED from R6): per-bucket counting sort -> offsets[] +
// per-node-grouped sw, 1024 threads/block, seg cached in registers.
// ---------------------------------------------------------------------------
__global__ __launch_bounds__(1024) void passB(const int* __restrict__ gcur,
                                              const uint2* __restrict__ tmp,
                                              int* __restrict__ offsets,
                                              uint2* __restrict__ sw) {
    __shared__ int hist[256], ps[256];
    int b = blockIdx.x, t = threadIdx.x;

    if (t < 256) ps[t] = (t < b) ? gcur[t * GSTRIDE] : 0;
    __syncthreads();
    for (int off = 128; off > 0; off >>= 1) {
        if (t < off) ps[t] += ps[t + off];
        __syncthreads();
    }
    int base = ps[0];
    int cnt = gcur[b * GSTRIDE];
    if (t < 256) hist[t] = 0;
    __syncthreads();

    const uint2* seg = tmp + (size_t)b * CAP;
    uint2 ent[5];
#pragma unroll
    for (int j = 0; j < 5; ++j) {
        int i = t + j * 1024;
        if (i < cnt) {
            ent[j] = seg[i];
            atomicAdd(&hist[ent[j].x >> 16], 1);
        }
    }
    __syncthreads();

    int h = 0;
    if (t < 256) { h = hist[t]; ps[t] = h; }
    __syncthreads();
    for (int off = 1; off < 256; off <<= 1) {
        int x = 0;
        if (t < 256 && t >= off) x = ps[t - off];
        __syncthreads();
        if (t < 256) ps[t] += x;
        __syncthreads();
    }
    int o = 0;
    if (t < 256) {
        o = base + ps[t] - h;  // exclusive within-bucket + bucket base
        int node = b * 256 + t;
        if (node < N_NODES) offsets[node] = o;
    }
    if (b == NBUCK - 1 && t == 0) offsets[N_NODES] = N_EDGES;
    __syncthreads();
    if (t < 256) hist[t] = o;  // reuse as cursor
    __syncthreads();
#pragma unroll
    for (int j = 0; j < 5; ++j) {
        int i = t + j * 1024;
        if (i < cnt) {
            int pos = atomicAdd(&hist[ent[j].x >> 16], 1);
            sw[pos] = make_uint2(ent[j].x & 0xffffu, ent[j].y);
        }
    }
}

// ---------------------------------------------------------------------------
// K3 (REVERTED to the R4/R6 proven 47.5us version). History of attempts on
// this kernel, all counter-verified:
//   R5  LDS-staged sw          -> 70us (broke the ~32-loads-in-flight window)
//   R7  dwordx2 batch-32 probe -> 220us (p[32] spilled to scratch: VGPR=56,
//                                  WRITE_SIZE 818MB of scratch traffic)
// This structure sits ~13% above the compulsory-traffic floor: fb (12.8MB)
// must re-fill each of 8 non-coherent XCD L2s (~102MB L2-miss minimum);
// measured FETCH 86.7MB at 2.42-2.50 TB/s effective across 3 runs.
// Block = 16 nodes, wave aggregates 4. __launch_bounds__(256,2) lifts the
// VGPR cap so p[16]+u[16]+pn[16] stay live. Tail batch clamp-padded with
// weights zeroed. Then blended bf16 rows -> Arows -> 16x128 @ 128x128 MFMA.
// mfma_f32_16x16x32_bf16: A[m=lane&15][k=quad*8+j], B[k][n=lane&15],
// D row=quad*4+reg, col=lane&15 (verified in prior rounds).
// ---------------------------------------------------------------------------
__global__ __launch_bounds__(256, 2) void agg_gemm(const int* __restrict__ offsets,
                                                   const uint2* __restrict__ sw,
                                                   const unsigned* __restrict__ fb,
                                                   const unsigned short* __restrict__ Wt,
                                                   float* __restrict__ out) {
    __shared__ unsigned Arows[16][68];
    int wave = threadIdx.x >> 6;
    int lane = threadIdx.x & 63;
    int row0 = blockIdx.x * 16;

#pragma unroll 1
    for (int i = 0; i < 4; ++i) {
        int n = __builtin_amdgcn_readfirstlane(row0 + wave * 4 + i);
        int b = offsets[n], e2 = offsets[n + 1];
        unsigned us = fb[(size_t)n * 64 + lane];  // self row
        float ax = 0.f, ay = 0.f;
        int e = b;
        int nfull = (e2 - b) >> 4;

        uint2 p[16];
        {   // preload first batch (clamped; OOB-safe: sw is followed by fb in ws)
            int rem = e2 - e;
#pragma unroll
            for (int j = 0; j < 16; ++j) {
                int idx = (j < rem) ? j : (rem > 0 ? rem - 1 : 0);
                p[j] = sw[e + idx];
            }
        }
#pragma unroll 1
        for (int t = 0; t < nfull; ++t) {
            unsigned u[16];
#pragma unroll
            for (int j = 0; j < 16; ++j) u[j] = fb[(size_t)p[j].x * 64 + lane];
            // prefetch next batch while the 16 gathers are in flight
            int en = e + 16;
            int rem = e2 - en;
            uint2 pn[16];
#pragma unroll
            for (int j = 0; j < 16; ++j) {
                int idx = (j < rem) ? j : (rem > 0 ? rem - 1 : 0);
                pn[j] = sw[en + idx];
            }
#pragma unroll
            for (int j = 0; j < 16; ++j) {
                float w = __uint_as_float(p[j].y);
                ax += w * lo16f(u[j]);
                ay += w * hi16f(u[j]);
            }
#pragma unroll
            for (int j = 0; j < 16; ++j) p[j] = pn[j];
            e = en;
        }
        int rem = e2 - e;
        if (rem > 0) {  // tail: p already holds the clamp-padded batch
            unsigned u[16];
#pragma unroll
            for (int j = 0; j < 16; ++j) u[j] = fb[(size_t)p[j].x * 64 + lane];
#pragma unroll
            for (int j = 0; j < 16; ++j) {
                float w = (j < rem) ? __uint_as_float(p[j].y) : 0.f;
                ax += w * lo16f(u[j]);
                ay += w * hi16f(u[j]);
            }
        }
        float rx = 0.5f * (ax + lo16f(us));
        float ry = 0.5f * (ay + hi16f(us));
        Arows[wave * 4 + i][lane] = (unsigned)f2bf(rx) | ((unsigned)f2bf(ry) << 16);
    }
    __syncthreads();

    int quad = lane >> 4;
    int col  = lane & 15;
    short8 a[4];
#pragma unroll
    for (int kk = 0; kk < 4; ++kk)
        a[kk] = *reinterpret_cast<const short8*>(&Arows[col][kk * 16 + quad * 4]);

#pragma unroll
    for (int ii = 0; ii < 2; ++ii) {
        int n0 = wave * 2 + ii;
        const short8* bp = reinterpret_cast<const short8*>(Wt) + ((n0 * 16 + col) * 16 + quad);
        f32x4 acc = {0.f, 0.f, 0.f, 0.f};
        acc = __builtin_amdgcn_mfma_f32_16x16x32_bf16(a[0], bp[0],  acc, 0, 0, 0);
        acc = __builtin_amdgcn_mfma_f32_16x16x32_bf16(a[1], bp[4],  acc, 0, 0, 0);
        acc = __builtin_amdgcn_mfma_f32_16x16x32_bf16(a[2], bp[8],  acc, 0, 0, 0);
        acc = __builtin_amdgcn_mfma_f32_16x16x32_bf16(a[3], bp[12], acc, 0, 0, 0);
#pragma unroll
        for (int rr = 0; rr < 4; ++rr)
            out[(size_t)(row0 + quad * 4 + rr) * D + n0 * 16 + col] = acc[rr];
    }
}

// ---------------------------------------------------------------------------
extern "C" void kernel_launch(void* const* d_in, const int* in_sizes, int n_in,
                              void* d_out, int out_size, void* d_ws, size_t ws_size,
                              hipStream_t stream) {
    const float* feat = (const float*)d_in[0];
    const int*   esrc = (const int*)d_in[1];
    const int*   edst = (const int*)d_in[2];
    const float* ew   = (const float*)d_in[3];
    const float* W    = (const float*)d_in[4];
    float*       out  = (float*)d_out;

    char* ws = (char*)d_ws;
    uint2*          sw      = (uint2*)(ws + 0);                   //  6,400,000
    unsigned*       fb      = (unsigned*)(ws + 6400000);          // 12,800,000
    int*            offsets = (int*)(ws + 19200000);              //    200,004
    unsigned short* Wt      = (unsigned short*)(ws + 19400064);   //     32,768
    int*            gcur    = (int*)(ws + 19432832);              //  12,544 (padded)
    // tmp (7.53 MB) aliases d_out, dead until agg_gemm overwrites it.
    uint2* tmp = (uint2*)d_out;

    hipMemsetAsync(gcur, 0, NBUCK * GSTRIDE * sizeof(int), stream);
    prep_passA<<<PA_BLKS + FB_BLKS + WT_BLKS, 1024, 0, stream>>>(
        (const float2*)feat, fb, W, Wt, esrc, edst, ew, gcur, tmp);
    passB<<<NBUCK, 1024, 0, stream>>>(gcur, tmp, offsets, sw);
    agg_gemm<<<N_NODES / 16, 256, 0, stream>>>(offsets, sw, fb, Wt, out);
}